// Round 1
// baseline (1486.981 us; speedup 1.0000x reference)
//
#include <hip/hip_runtime.h>

typedef unsigned short u16;
typedef unsigned int u32;
typedef __bf16 bf16x8 __attribute__((ext_vector_type(8)));
typedef float f32x4 __attribute__((ext_vector_type(4)));
typedef u16 u16x4 __attribute__((ext_vector_type(4)));
typedef u16 u16x8 __attribute__((ext_vector_type(8)));

#define MFMA16(a,b,c) __builtin_amdgcn_mfma_f32_16x16x32_bf16((a),(b),(c),0,0,0)

__device__ __forceinline__ u16 f2bf(float f) {
  u32 u = __builtin_bit_cast(u32, f);
  u += 0x7fffu + ((u >> 16) & 1u);   // RNE
  return (u16)(u >> 16);
}
__device__ __forceinline__ float bf2f(u16 h) {
  return __builtin_bit_cast(float, (u32)h << 16);
}

// ---------------------------------------------------------------------------
// Transpose + convert weights: Wt[n][k] = bf16(W[k][n]).  z selects matrix.
// grid (32,32,3), block (32,8)
__global__ void wtrans_k(const float* __restrict__ Wq2, const float* __restrict__ Wk2,
                         const float* __restrict__ Wv, u16* __restrict__ Tq,
                         u16* __restrict__ Tk, u16* __restrict__ Tv)
{
  __shared__ float tile[32][33];
  const float* src; u16* dst;
  if (blockIdx.z == 0)      { src = Wq2;             dst = Tq; }
  else if (blockIdx.z == 1) { src = Wk2;             dst = Tk; }
  else                      { src = Wv + 1024*1024;  dst = Tv; }  // bottom half of Wv
  const int k0 = blockIdx.x * 32, n0 = blockIdx.y * 32;
  const int tx = threadIdx.x, ty = threadIdx.y;
#pragma unroll
  for (int j = 0; j < 4; ++j)
    tile[ty + 8*j][tx] = src[(size_t)(k0 + ty + 8*j) * 1024 + n0 + tx];
  __syncthreads();
#pragma unroll
  for (int j = 0; j < 4; ++j)
    dst[(size_t)(n0 + ty + 8*j) * 1024 + k0 + tx] = f2bf(tile[tx][ty + 8*j]);
}

// ---------------------------------------------------------------------------
// v1bv[b][d] = bv[d] + sum_j X1[b][j] * Wv[j][d]   (top half of Wv)
// grid (4,8), block 256
__global__ void v1bv_k(const float* __restrict__ X1, const float* __restrict__ Wv,
                       const float* __restrict__ bv, float* __restrict__ v1bv)
{
  const int b = blockIdx.y;
  const int d = blockIdx.x * 256 + threadIdx.x;
  float acc = bv[d];
  for (int j = 0; j < 1024; ++j)
    acc = fmaf(X1[b*1024 + j], Wv[(size_t)j*1024 + d], acc);
  v1bv[b*1024 + d] = acc;
}

// ---------------------------------------------------------------------------
// GEMM: C = bf16( X2(fp32)[M,1024] @ W + bias ).  W given transposed bf16 Wt[n][k].
// mode 0: C row-major [M][1024], bias[n]
// mode 1: C transposed into Vt[b][n][s] (s = row % 2048), bias = biasB[b*1024+n]
// grid (8 n-blocks, 128 m-blocks), block 256 (4 waves, 2x2 of 64x64)
__global__ __launch_bounds__(256, 2) void gemm_proj(
    const float* __restrict__ A, const u16* __restrict__ Bt,
    const float* __restrict__ bias, const float* __restrict__ biasB,
    u16* __restrict__ C, int mode)
{
  __shared__ __attribute__((aligned(16))) u16 ldsA[128 * 72];  // stride 72 u16 = 144B
  __shared__ __attribute__((aligned(16))) u16 ldsB[128 * 72];
  const int t = threadIdx.x;
  const int lane = t & 63, w = t >> 6;
  const int wr = w >> 1, wc = w & 1;
  const int l15 = lane & 15, l4 = lane >> 4;
  const int n0 = blockIdx.x * 128;
  const int m0 = blockIdx.y * 128;
  const int srow = t >> 1, shalf = (t & 1) * 32;

  const float* aS = A  + (size_t)(m0 + srow) * 1024 + shalf;
  const u16*   bS = Bt + (size_t)(n0 + srow) * 1024 + shalf;
  u16* aD = &ldsA[srow * 72 + shalf];
  u16* bD = &ldsB[srow * 72 + shalf];

  f32x4 acc[4][4];
#pragma unroll
  for (int i = 0; i < 4; ++i)
#pragma unroll
    for (int j = 0; j < 4; ++j) acc[i][j] = (f32x4){0.f, 0.f, 0.f, 0.f};

  for (int kt = 0; kt < 16; ++kt) {
    __syncthreads();
    const f32x4* ap = (const f32x4*)(aS + (size_t)kt * 64);
    f32x4 av[8];
#pragma unroll
    for (int q = 0; q < 8; ++q) av[q] = ap[q];
    const u16x8* bp = (const u16x8*)(bS + (size_t)kt * 64);
    u16x8 bv4[4];
#pragma unroll
    for (int q = 0; q < 4; ++q) bv4[q] = bp[q];
#pragma unroll
    for (int q = 0; q < 4; ++q) {
      u16x8 wv;
#pragma unroll
      for (int j = 0; j < 4; ++j) { wv[j] = f2bf(av[2*q][j]); wv[4+j] = f2bf(av[2*q+1][j]); }
      *(u16x8*)(aD + q * 8) = wv;
      *(u16x8*)(bD + q * 8) = bv4[q];
    }
    __syncthreads();
#pragma unroll
    for (int inner = 0; inner < 2; ++inner) {
      bf16x8 af[4], bf_[4];
#pragma unroll
      for (int i = 0; i < 4; ++i)
        af[i] = *(const bf16x8*)&ldsA[(64*wr + 16*i + l15) * 72 + inner*32 + l4*8];
#pragma unroll
      for (int j = 0; j < 4; ++j)
        bf_[j] = *(const bf16x8*)&ldsB[(64*wc + 16*j + l15) * 72 + inner*32 + l4*8];
#pragma unroll
      for (int i = 0; i < 4; ++i)
#pragma unroll
        for (int j = 0; j < 4; ++j)
          acc[i][j] = MFMA16(af[i], bf_[j], acc[i][j]);
    }
  }

  const int b = m0 >> 11;
  if (mode == 0) {
#pragma unroll
    for (int j = 0; j < 4; ++j) {
      const int gc = n0 + 64*wc + 16*j + l15;
      const float bb = bias[gc];
#pragma unroll
      for (int i = 0; i < 4; ++i) {
        const int gr = m0 + 64*wr + 16*i + l4*4;
#pragma unroll
        for (int r = 0; r < 4; ++r)
          C[(size_t)(gr + r) * 1024 + gc] = f2bf(acc[i][j][r] + bb);
      }
    }
  } else {
#pragma unroll
    for (int j = 0; j < 4; ++j) {
      const int gc = n0 + 64*wc + 16*j + l15;            // d
      const float bb = biasB[b*1024 + gc];
#pragma unroll
      for (int i = 0; i < 4; ++i) {
        const int s = (m0 & 2047) + 64*wr + 16*i + l4*4; // seq pos
        u16x4 pk;
#pragma unroll
        for (int r = 0; r < 4; ++r) pk[r] = f2bf(acc[i][j][r] + bb);
        *(u16x4*)(C + (size_t)b*1024*2048 + (size_t)gc*2048 + s) = pk;
      }
    }
  }
}

// ---------------------------------------------------------------------------
// Vsum[row] = sum_s Vt[row][s]  (row = b*1024+d, 2048 bf16 each)
// grid 2048, block 256 (4 waves, one row per wave)
__global__ void vsum_k(const u16* __restrict__ Vt, float* __restrict__ Vsum)
{
  const int row = blockIdx.x * 4 + (threadIdx.x >> 6);
  const int lane = threadIdx.x & 63;
  const u16* rp = Vt + (size_t)row * 2048;
  float s = 0.f;
#pragma unroll
  for (int p = 0; p < 4; ++p) {
    u16x8 v = *(const u16x8*)(rp + p*512 + lane*8);
#pragma unroll
    for (int j = 0; j < 8; ++j) s += bf2f(v[j]);
  }
#pragma unroll
  for (int o = 32; o; o >>= 1) s += __shfl_xor(s, o);
  if (lane == 0) Vsum[row] = s;
}

// ---------------------------------------------------------------------------
// Flash attention: out[b,q,:] = softmax(Q2 K2^T / 32) @ V  -  (alpha/2048)*Vsum
// grid 512 (1-D; b = id&7 pins batch->XCD), block 512 (8 waves).
// Block: 32 q-rows; KV tile 128; wave w: S cols 16w..16w+15 and O cols 128w..+127.
__global__ __launch_bounds__(512, 2) void attn_k(
    const u16* __restrict__ Q2, const u16* __restrict__ K2,
    const u16* __restrict__ Vt, const float* __restrict__ Vsum,
    const float* __restrict__ alphaP, float* __restrict__ out)
{
  __shared__ __attribute__((aligned(16))) float Sbuf[32 * 132]; // raw scores, stride 132 f32
  __shared__ __attribute__((aligned(16))) u16 Pbuf[32 * 136];   // bf16 P, stride 136 u16
  __shared__ float Crow[32];
  __shared__ float Lrow[32];

  const int id = blockIdx.x;
  const int b = id & 7, qt = id >> 3;
  const int t = threadIdx.x, lane = t & 63, w = t >> 6;
  const int l15 = lane & 15, l4 = lane >> 4;
  const int qbase = qt * 32;
  const u16* Qb = Q2 + ((size_t)(b*2048 + qbase)) * 1024;
  const u16* Kb = K2 + (size_t)b * 2048 * 1024;
  const u16* Vb = Vt + (size_t)b * 1024 * 2048;
  const float scale = 0.03125f;  // 1/sqrt(1024)

  f32x4 acc[2][8];
#pragma unroll
  for (int i = 0; i < 2; ++i)
#pragma unroll
    for (int j = 0; j < 8; ++j) acc[i][j] = (f32x4){0.f, 0.f, 0.f, 0.f};

  const int prow = 4*w + l4;            // row this lane owns for softmax stats
  float m_run = -3.0e38f, l_run = 0.f;  // replicated across the 16 l15 lanes

  const u16* qp0 = Qb + (size_t)l15 * 1024 + l4*8;
  const u16* qp1 = qp0 + 16 * 1024;
  const u16* kpB = Kb + (size_t)(16*w + l15) * 1024 + l4*8;

  for (int kt = 0; kt < 16; ++kt) {
    const int k0 = kt * 128;
    // ---- S = Q K^T (raw, unscaled). Wave w: cols 16w..16w+15, rows 0..31.
    const u16* kp = kpB + (size_t)k0 * 1024;
    f32x4 s00 = {0.f,0.f,0.f,0.f}, s01 = {0.f,0.f,0.f,0.f};
    f32x4 s10 = {0.f,0.f,0.f,0.f}, s11 = {0.f,0.f,0.f,0.f};
#pragma unroll 4
    for (int kk = 0; kk < 32; ++kk) {
      bf16x8 kf = *(const bf16x8*)(kp + kk*32);
      bf16x8 q0 = *(const bf16x8*)(qp0 + kk*32);
      bf16x8 q1 = *(const bf16x8*)(qp1 + kk*32);
      if (kk & 1) { s01 = MFMA16(q0, kf, s01); s11 = MFMA16(q1, kf, s11); }
      else        { s00 = MFMA16(q0, kf, s00); s10 = MFMA16(q1, kf, s10); }
    }
    f32x4 sc0 = s00 + s01, sc1 = s10 + s11;
#pragma unroll
    for (int r = 0; r < 4; ++r) {
      Sbuf[(l4*4 + r)      * 132 + 16*w + l15] = sc0[r];
      Sbuf[(16 + l4*4 + r) * 132 + 16*w + l15] = sc1[r];
    }
    __syncthreads();  // B1: Sbuf complete

    // ---- online softmax; lane owns row prow, cols l15*8 .. +7
    {
      const float* srp = &Sbuf[prow * 132 + l15*8];
      f32x4 v0 = *(const f32x4*)srp;
      f32x4 v1 = *(const f32x4*)(srp + 4);
      float lmax = fmaxf(fmaxf(fmaxf(v0[0],v0[1]),fmaxf(v0[2],v0[3])),
                         fmaxf(fmaxf(v1[0],v1[1]),fmaxf(v1[2],v1[3])));
#pragma unroll
      for (int m = 1; m < 16; m <<= 1) lmax = fmaxf(lmax, __shfl_xor(lmax, m));
      const float m_new = fmaxf(m_run, lmax * scale);
      const float corr = __expf(m_run - m_new);
      float p[8]; float rs = 0.f;
#pragma unroll
      for (int j = 0; j < 4; ++j) { p[j]   = __expf(v0[j]*scale - m_new); rs += p[j]; }
#pragma unroll
      for (int j = 0; j < 4; ++j) { p[4+j] = __expf(v1[j]*scale - m_new); rs += p[4+j]; }
#pragma unroll
      for (int m = 1; m < 16; m <<= 1) rs += __shfl_xor(rs, m);
      l_run = l_run * corr + rs;
      m_run = m_new;
      u16x8 pk;
#pragma unroll
      for (int j = 0; j < 8; ++j) pk[j] = f2bf(p[j]);
      *(u16x8*)&Pbuf[prow * 136 + l15*8] = pk;
      if (l15 == 0) Crow[prow] = corr;
    }
    __syncthreads();  // B2: Pbuf + Crow complete

    // ---- rescale O by corr per row
    float cf0[4], cf1[4];
#pragma unroll
    for (int r = 0; r < 4; ++r) { cf0[r] = Crow[l4*4 + r]; cf1[r] = Crow[16 + l4*4 + r]; }
#pragma unroll
    for (int nj = 0; nj < 8; ++nj)
#pragma unroll
      for (int r = 0; r < 4; ++r) { acc[0][nj][r] *= cf0[r]; acc[1][nj][r] *= cf1[r]; }

    // ---- O += P @ V   (wave's 128 output cols)
#pragma unroll
    for (int inner = 0; inner < 4; ++inner) {
      bf16x8 p0 = *(const bf16x8*)&Pbuf[l15        * 136 + inner*32 + l4*8];
      bf16x8 p1 = *(const bf16x8*)&Pbuf[(16 + l15) * 136 + inner*32 + l4*8];
      const u16* vbase = Vb + (size_t)(128*w + l15) * 2048 + k0 + inner*32 + l4*8;
#pragma unroll
      for (int nj = 0; nj < 8; ++nj) {
        bf16x8 vv = *(const bf16x8*)(vbase + (size_t)nj * 16 * 2048);
        acc[0][nj] = MFMA16(p0, vv, acc[0][nj]);
        acc[1][nj] = MFMA16(p1, vv, acc[1][nj]);
      }
    }
  }

  // ---- epilogue: divide by l, subtract alpha/2048 * Vsum, write fp32
  if (l15 == 0) Lrow[prow] = l_run;
  __syncthreads();
  float li0[4], li1[4];
#pragma unroll
  for (int r = 0; r < 4; ++r) {
    li0[r] = 1.f / Lrow[l4*4 + r];
    li1[r] = 1.f / Lrow[16 + l4*4 + r];
  }
  const float aS_ = alphaP[0] * (1.0f / 2048.0f);
#pragma unroll
  for (int nj = 0; nj < 8; ++nj) {
    const int col = 128*w + 16*nj + l15;
    const float ct = aS_ * Vsum[b*1024 + col];
    const size_t rb0 = (size_t)(b*2048 + qbase + l4*4) * 1024 + col;
#pragma unroll
    for (int r = 0; r < 4; ++r) {
      out[rb0 + (size_t)r*1024]            = acc[0][nj][r] * li0[r] - ct;
      out[rb0 + (size_t)(16 + r)*1024]     = acc[1][nj][r] * li1[r] - ct;
    }
  }
}

// ---------------------------------------------------------------------------
extern "C" void kernel_launch(void* const* d_in, const int* in_sizes, int n_in,
                              void* d_out, int out_size, void* d_ws, size_t ws_size,
                              hipStream_t stream)
{
  const float* X1  = (const float*)d_in[0];
  const float* X2  = (const float*)d_in[1];
  const float* Wq2 = (const float*)d_in[4];
  const float* bq2 = (const float*)d_in[5];
  const float* Wk2 = (const float*)d_in[8];
  const float* bk2 = (const float*)d_in[9];
  const float* Wv  = (const float*)d_in[10];
  const float* bv  = (const float*)d_in[11];
  const float* alpha = (const float*)d_in[12];
  float* out = (float*)d_out;

  char* ws = (char*)d_ws;
  u16* Q2 = (u16*)(ws);                       // 32 MB
  u16* K2 = (u16*)(ws + 33554432);            // 32 MB
  u16* Vt = (u16*)(ws + 67108864);            // 32 MB  [b][d][s]
  u16* Tq = (u16*)(ws + 100663296);           // 2 MB
  u16* Tk = (u16*)(ws + 102760448);           // 2 MB
  u16* Tv = (u16*)(ws + 104857600);           // 2 MB
  float* v1bv = (float*)(ws + 106954752);     // 32 KB
  float* Vsum = (float*)(ws + 106987520);     // 32 KB

  wtrans_k<<<dim3(32, 32, 3), dim3(32, 8), 0, stream>>>(Wq2, Wk2, Wv, Tq, Tk, Tv);
  v1bv_k<<<dim3(4, 8), 256, 0, stream>>>(X1, Wv, bv, v1bv);
  gemm_proj<<<dim3(8, 128), 256, 0, stream>>>(X2, Tq, bq2, nullptr, Q2, 0);
  gemm_proj<<<dim3(8, 128), 256, 0, stream>>>(X2, Tk, bk2, nullptr, K2, 0);
  gemm_proj<<<dim3(8, 128), 256, 0, stream>>>(X2, Tv, nullptr, v1bv, Vt, 1);
  vsum_k<<<2048, 256, 0, stream>>>(Vt, Vsum);
  attn_k<<<512, 512, 0, stream>>>(Q2, K2, Vt, Vsum, alpha, out);
}

// Round 4
// 561.729 us; speedup vs baseline: 2.6471x; 2.6471x over previous
//
#include <hip/hip_runtime.h>

typedef unsigned short u16;
typedef unsigned int u32;
typedef __bf16 bf16x8 __attribute__((ext_vector_type(8)));
typedef float f32x4 __attribute__((ext_vector_type(4)));
typedef u16 u16x4 __attribute__((ext_vector_type(4)));
typedef u16 u16x8 __attribute__((ext_vector_type(8)));

#define MFMA16(a,b,c) __builtin_amdgcn_mfma_f32_16x16x32_bf16((a),(b),(c),0,0,0)

__device__ __forceinline__ u16 f2bf(float f) {
  u32 u = __builtin_bit_cast(u32, f);
  u += 0x7fffu + ((u >> 16) & 1u);   // RNE
  return (u16)(u >> 16);
}
__device__ __forceinline__ float bf2f(u16 h) {
  return __builtin_bit_cast(float, (u32)h << 16);
}

typedef __attribute__((address_space(1))) const void gas_void;
typedef __attribute__((address_space(3))) void las_void;
__device__ __forceinline__ void gld16(const void* g, void* l) {
  __builtin_amdgcn_global_load_lds((gas_void*)g, (las_void*)l, 16, 0, 0);
}

// ---------------------------------------------------------------------------
// Transpose + convert weights: Wt[n][k] = bf16(W[k][n]).  z selects matrix.
__global__ void wtrans_k(const float* __restrict__ Wq2, const float* __restrict__ Wk2,
                         const float* __restrict__ Wv, u16* __restrict__ Tq,
                         u16* __restrict__ Tk, u16* __restrict__ Tv)
{
  __shared__ float tile[32][33];
  const float* src; u16* dst;
  if (blockIdx.z == 0)      { src = Wq2;             dst = Tq; }
  else if (blockIdx.z == 1) { src = Wk2;             dst = Tk; }
  else                      { src = Wv + 1024*1024;  dst = Tv; }  // bottom half of Wv
  const int k0 = blockIdx.x * 32, n0 = blockIdx.y * 32;
  const int tx = threadIdx.x, ty = threadIdx.y;
#pragma unroll
  for (int j = 0; j < 4; ++j)
    tile[ty + 8*j][tx] = src[(size_t)(k0 + ty + 8*j) * 1024 + n0 + tx];
  __syncthreads();
#pragma unroll
  for (int j = 0; j < 4; ++j)
    dst[(size_t)(n0 + ty + 8*j) * 1024 + k0 + tx] = f2bf(tile[tx][ty + 8*j]);
}

// ---------------------------------------------------------------------------
// X2 (fp32) -> bf16, 8 elems/thread
__global__ void x2bf_k(const float* __restrict__ X2, u16* __restrict__ X2b)
{
  const size_t i = ((size_t)blockIdx.x * 256 + threadIdx.x) * 8;
  f32x4 a = *(const f32x4*)(X2 + i);
  f32x4 b = *(const f32x4*)(X2 + i + 4);
  u16x8 o;
#pragma unroll
  for (int j = 0; j < 4; ++j) { o[j] = f2bf(a[j]); o[4+j] = f2bf(b[j]); }
  *(u16x8*)(X2b + i) = o;
}

// ---------------------------------------------------------------------------
// v1bv[b][d] = bv[d] + sum_j X1[b][j] * Wv[j][d]  (top half of Wv)
// grid (16, 8), block 256: 64 d-cols per block, j split 4 ways
__global__ void v1bv_k(const float* __restrict__ X1, const float* __restrict__ Wv,
                       const float* __restrict__ bv, float* __restrict__ v1bv)
{
  const int b = blockIdx.y, t = threadIdx.x;
  const int d = blockIdx.x * 64 + (t & 63);
  const int jg = t >> 6;
  float a = 0.f;
#pragma unroll 8
  for (int jj = 0; jj < 256; ++jj) {
    const int j = jg * 256 + jj;
    a = fmaf(X1[b*1024 + j], Wv[(size_t)j * 1024 + d], a);
  }
  __shared__ float red[256];
  red[t] = a;
  __syncthreads();
  if (t < 64)
    v1bv[b*1024 + d] = red[t] + red[t+64] + red[t+128] + red[t+192] + bv[d];
}

// ---------------------------------------------------------------------------
// m97-style GEMM: C = (A[M,K] @ B[N,K]^T + bias) * cscale, bf16 out.
// A,B bf16 row-major (row stride == K). global_load_lds staging both operands.
// mode 0: C row-major [.][ldC] (bias[n] optional)
// mode 1: C transposed Vt[b][n][s], bias = biasB[b*1024+n]
// grid (N/128, M/128, Z), block 256 (4 waves, 2x2 of 64x64)
__global__ __launch_bounds__(256, 2) void gemm_bf16(
    const u16* __restrict__ A, const u16* __restrict__ B,
    const float* __restrict__ bias, const float* __restrict__ biasB,
    u16* __restrict__ C, int K, int ldC, int mode, float cscale,
    size_t sA, size_t sB, size_t sC)
{
  __shared__ __attribute__((aligned(16))) u16 ldsA[128 * 64];
  __shared__ __attribute__((aligned(16))) u16 ldsB[128 * 64];
  const int t = threadIdx.x, lane = t & 63, w = t >> 6;
  const int wr = w >> 1, wc = w & 1, l15 = lane & 15, l4 = lane >> 4;
  const int z = blockIdx.z;
  const u16* Ab = A + (size_t)z * sA;
  const u16* Bb = B + (size_t)z * sB;
  u16* Cb = C + (size_t)z * sC;
  const int n0 = blockIdx.x * 128, m0 = blockIdx.y * 128;

  // staging map: wave w, iter i -> LDS bytes [w*4096 + i*1024, +1KB), lane*16 by HW
  const int ebase = w * 2048 + lane * 8;  // + i*512

  f32x4 acc[4][4];
#pragma unroll
  for (int i = 0; i < 4; ++i)
#pragma unroll
    for (int j = 0; j < 4; ++j) acc[i][j] = (f32x4){0.f, 0.f, 0.f, 0.f};

  const int nkt = K >> 6;
  for (int kt = 0; kt < nkt; ++kt) {
    const int k0 = kt * 64;
    __syncthreads();
#pragma unroll
    for (int i = 0; i < 4; ++i) {
      const int elem = ebase + i * 512;
      const int row = elem >> 6, col = elem & 63;
      gld16(Ab + (size_t)(m0 + row) * K + k0 + col, (char*)ldsA + w*4096 + i*1024);
      gld16(Bb + (size_t)(n0 + row) * K + k0 + col, (char*)ldsB + w*4096 + i*1024);
    }
    __syncthreads();
#pragma unroll
    for (int inner = 0; inner < 2; ++inner) {
      bf16x8 af[4], bfr[4];
#pragma unroll
      for (int i = 0; i < 4; ++i)
        af[i] = *(const bf16x8*)&ldsA[(64*wr + 16*i + l15) * 64 + inner*32 + l4*8];
#pragma unroll
      for (int j = 0; j < 4; ++j)
        bfr[j] = *(const bf16x8*)&ldsB[(64*wc + 16*j + l15) * 64 + inner*32 + l4*8];
#pragma unroll
      for (int i = 0; i < 4; ++i)
#pragma unroll
        for (int j = 0; j < 4; ++j)
          acc[i][j] = MFMA16(af[i], bfr[j], acc[i][j]);
    }
  }

  if (mode == 0) {
#pragma unroll
    for (int j = 0; j < 4; ++j) {
      const int gc = n0 + 64*wc + 16*j + l15;
      const float bb = bias ? bias[gc] : 0.f;
#pragma unroll
      for (int i = 0; i < 4; ++i) {
        const int gr = m0 + 64*wr + 16*i + l4*4;
#pragma unroll
        for (int r = 0; r < 4; ++r)
          Cb[(size_t)(gr + r) * ldC + gc] = f2bf((acc[i][j][r] + bb) * cscale);
      }
    }
  } else {
    const int b = m0 >> 11;
#pragma unroll
    for (int j = 0; j < 4; ++j) {
      const int gc = n0 + 64*wc + 16*j + l15;            // d
      const float bb = biasB[b*1024 + gc];
#pragma unroll
      for (int i = 0; i < 4; ++i) {
        const int s = (m0 & 2047) + 64*wr + 16*i + l4*4; // seq pos
        u16x4 pk;
#pragma unroll
        for (int r = 0; r < 4; ++r) pk[r] = f2bf(acc[i][j][r] + bb);
        *(u16x4*)(Cb + (size_t)b*1024*2048 + (size_t)gc*2048 + s) = pk;
      }
    }
  }
}

// ---------------------------------------------------------------------------
// Vsum[row] = sum_s Vt[row][s]  (row = b*1024+d)
__global__ void vsum_k(const u16* __restrict__ Vt, float* __restrict__ Vsum)
{
  const int row = blockIdx.x * 4 + (threadIdx.x >> 6);
  const int lane = threadIdx.x & 63;
  const u16* rp = Vt + (size_t)row * 2048;
  float s = 0.f;
#pragma unroll
  for (int p = 0; p < 4; ++p) {
    u16x8 v = *(const u16x8*)(rp + p*512 + lane*8);
#pragma unroll
    for (int j = 0; j < 8; ++j) s += bf2f(v[j]);
  }
#pragma unroll
  for (int o = 32; o; o >>= 1) s += __shfl_xor(s, o);
  if (lane == 0) Vsum[row] = s;
}

// ---------------------------------------------------------------------------
// In-place: S (scaled logits bf16, rows of 2048) -> P = exp(S); linv = 1/rowsum(P).
// No row max needed: logits ~N(0,1), fp32 exp safe. One wave per row.
__global__ void rowexp_k(u16* __restrict__ S, float* __restrict__ linv)
{
  const int row = blockIdx.x * 4 + (threadIdx.x >> 6);
  const int lane = threadIdx.x & 63;
  u16* rp = S + (size_t)row * 2048;
  float s = 0.f;
#pragma unroll
  for (int p = 0; p < 4; ++p) {
    u16x8 v = *(u16x8*)(rp + p*512 + lane*8);
    u16x8 o;
#pragma unroll
    for (int j = 0; j < 8; ++j) {
      const float e = __expf(bf2f(v[j]));
      s += e;
      o[j] = f2bf(e);
    }
    *(u16x8*)(rp + p*512 + lane*8) = o;
  }
#pragma unroll
  for (int o = 32; o; o >>= 1) s += __shfl_xor(s, o);
  if (lane == 0) linv[row] = 1.f / s;
}

// ---------------------------------------------------------------------------
// PV GEMM: out[b, q, d] = (P[b,q,:] @ Vt[b,d,:]) * linv[b*2048+q] - aS*Vsum[b,d]
// A = P [2048][2048] bf16 per batch, B = Vt [1024][2048] per batch. K = 2048.
// grid (8, 16, 8), block 256
__global__ __launch_bounds__(256, 2) void gemm_pv(
    const u16* __restrict__ P, const u16* __restrict__ Vt,
    const float* __restrict__ linv, const float* __restrict__ Vsum,
    const float* __restrict__ alphaP, float* __restrict__ out)
{
  __shared__ __attribute__((aligned(16))) u16 ldsA[128 * 64];
  __shared__ __attribute__((aligned(16))) u16 ldsB[128 * 64];
  const int t = threadIdx.x, lane = t & 63, w = t >> 6;
  const int wr = w >> 1, wc = w & 1, l15 = lane & 15, l4 = lane >> 4;
  const int b = blockIdx.z;
  const u16* Ab = P  + (size_t)b * 2048 * 2048;
  const u16* Bb = Vt + (size_t)b * 1024 * 2048;
  const int n0 = blockIdx.x * 128, m0 = blockIdx.y * 128;
  const int ebase = w * 2048 + lane * 8;

  f32x4 acc[4][4];
#pragma unroll
  for (int i = 0; i < 4; ++i)
#pragma unroll
    for (int j = 0; j < 4; ++j) acc[i][j] = (f32x4){0.f, 0.f, 0.f, 0.f};

  for (int kt = 0; kt < 32; ++kt) {
    const int k0 = kt * 64;
    __syncthreads();
#pragma unroll
    for (int i = 0; i < 4; ++i) {
      const int elem = ebase + i * 512;
      const int row = elem >> 6, col = elem & 63;
      gld16(Ab + (size_t)(m0 + row) * 2048 + k0 + col, (char*)ldsA + w*4096 + i*1024);
      gld16(Bb + (size_t)(n0 + row) * 2048 + k0 + col, (char*)ldsB + w*4096 + i*1024);
    }
    __syncthreads();
#pragma unroll
    for (int inner = 0; inner < 2; ++inner) {
      bf16x8 af[4], bfr[4];
#pragma unroll
      for (int i = 0; i < 4; ++i)
        af[i] = *(const bf16x8*)&ldsA[(64*wr + 16*i + l15) * 64 + inner*32 + l4*8];
#pragma unroll
      for (int j = 0; j < 4; ++j)
        bfr[j] = *(const bf16x8*)&ldsB[(64*wc + 16*j + l15) * 64 + inner*32 + l4*8];
#pragma unroll
      for (int i = 0; i < 4; ++i)
#pragma unroll
        for (int j = 0; j < 4; ++j)
          acc[i][j] = MFMA16(af[i], bfr[j], acc[i][j]);
    }
  }

  const float aS = alphaP[0] * (1.0f / 2048.0f);
#pragma unroll
  for (int j = 0; j < 4; ++j) {
    const int gc = n0 + 64*wc + 16*j + l15;  // d
    const float ct = aS * Vsum[b*1024 + gc];
#pragma unroll
    for (int i = 0; i < 4; ++i) {
      const int gr = m0 + 64*wr + 16*i + l4*4;  // q
#pragma unroll
      for (int r = 0; r < 4; ++r)
        out[(size_t)(b*2048 + gr + r) * 1024 + gc] =
            acc[i][j][r] * linv[b*2048 + gr + r] - ct;
    }
  }
}

// ---------------------------------------------------------------------------
extern "C" void kernel_launch(void* const* d_in, const int* in_sizes, int n_in,
                              void* d_out, int out_size, void* d_ws, size_t ws_size,
                              hipStream_t stream)
{
  const float* X1  = (const float*)d_in[0];
  const float* X2  = (const float*)d_in[1];
  const float* Wq2 = (const float*)d_in[4];
  const float* bq2 = (const float*)d_in[5];
  const float* Wk2 = (const float*)d_in[8];
  const float* bk2 = (const float*)d_in[9];
  const float* Wv  = (const float*)d_in[10];
  const float* bv  = (const float*)d_in[11];
  const float* alpha = (const float*)d_in[12];
  float* out = (float*)d_out;

  char* ws = (char*)d_ws;
  u16* Q2  = (u16*)(ws);                      // 32 MB  [16384][1024]
  u16* K2  = (u16*)(ws + 33554432);           // 32 MB
  u16* Vt  = (u16*)(ws + 67108864);           // 32 MB  [8][1024][2048]
  u16* S   = (u16*)(ws + 100663296);          // 64 MB  [8][2048][2048]
  u16* X2b = (u16*)(ws + 134217728);          // 32 MB, overlaps S upper half (dead before S-GEMM)
  u16* Tq  = (u16*)(ws + 167772160);          // 2 MB
  u16* Tk  = (u16*)(ws + 169869312);          // 2 MB
  u16* Tv  = (u16*)(ws + 171966464);          // 2 MB
  float* v1bv = (float*)(ws + 174063616);     // 32 KB
  float* Vsum = (float*)(ws + 174096384);     // 32 KB
  float* linv = (float*)(ws + 174129152);     // 64 KB

  const float qk_scale = 0.03125f;  // 1/sqrt(1024)

  wtrans_k<<<dim3(32, 32, 3), dim3(32, 8), 0, stream>>>(Wq2, Wk2, Wv, Tq, Tk, Tv);
  x2bf_k<<<8192, 256, 0, stream>>>(X2, X2b);
  v1bv_k<<<dim3(16, 8), 256, 0, stream>>>(X1, Wv, bv, v1bv);

  // projections: [16384,1024] = X2b @ T*^T (+bias)
  gemm_bf16<<<dim3(8, 128, 1), 256, 0, stream>>>(X2b, Tq, bq2, nullptr, Q2,
      1024, 1024, 0, 1.0f, 0, 0, 0);
  gemm_bf16<<<dim3(8, 128, 1), 256, 0, stream>>>(X2b, Tk, bk2, nullptr, K2,
      1024, 1024, 0, 1.0f, 0, 0, 0);
  gemm_bf16<<<dim3(8, 128, 1), 256, 0, stream>>>(X2b, Tv, nullptr, v1bv, Vt,
      1024, 0, 1, 1.0f, 0, 0, 0);

  vsum_k<<<2048, 256, 0, stream>>>(Vt, Vsum);

  // scores: S[b] = (Q2[b] @ K2[b]^T) * scale   (raw bf16, scaled)
  gemm_bf16<<<dim3(16, 16, 8), 256, 0, stream>>>(Q2, K2, nullptr, nullptr, S,
      1024, 2048, 0, qk_scale,
      (size_t)2048*1024, (size_t)2048*1024, (size_t)2048*2048);

  rowexp_k<<<4096, 256, 0, stream>>>(S, linv);

  gemm_pv<<<dim3(8, 16, 8), 256, 0, stream>>>(S, Vt, linv, Vsum, alpha, out);
}

// Round 5
// 502.961 us; speedup vs baseline: 2.9565x; 1.1168x over previous
//
#include <hip/hip_runtime.h>

typedef unsigned short u16;
typedef unsigned int u32;
typedef __bf16 bf16x8 __attribute__((ext_vector_type(8)));
typedef float f32x4 __attribute__((ext_vector_type(4)));
typedef u16 u16x4 __attribute__((ext_vector_type(4)));
typedef u16 u16x8 __attribute__((ext_vector_type(8)));

#define MFMA16(a,b,c) __builtin_amdgcn_mfma_f32_16x16x32_bf16((a),(b),(c),0,0,0)

__device__ __forceinline__ u16 f2bf(float f) {
  u32 u = __builtin_bit_cast(u32, f);
  u += 0x7fffu + ((u >> 16) & 1u);   // RNE
  return (u16)(u >> 16);
}
__device__ __forceinline__ float bf2f(u16 h) {
  return __builtin_bit_cast(float, (u32)h << 16);
}

typedef __attribute__((address_space(1))) const void gas_void;
typedef __attribute__((address_space(3))) void las_void;
__device__ __forceinline__ void gld16(const void* g, void* l) {
  __builtin_amdgcn_global_load_lds((gas_void*)g, (las_void*)l, 16, 0, 0);
}

// ---------------------------------------------------------------------------
// Zero rowsum (16384 f32) + Vsum (8192 f32) — contiguous 98304 B.
__global__ void init_k(float* __restrict__ p)
{
  const int i = blockIdx.x * 256 + threadIdx.x;
  ((f32x4*)p)[i] = (f32x4){0.f, 0.f, 0.f, 0.f};
}

// ---------------------------------------------------------------------------
// Transpose + convert weights: Wt[n][k] = bf16(W[k][n]).  z selects matrix.
__global__ void wtrans_k(const float* __restrict__ Wq2, const float* __restrict__ Wk2,
                         const float* __restrict__ Wv, u16* __restrict__ Tq,
                         u16* __restrict__ Tk, u16* __restrict__ Tv)
{
  __shared__ float tile[32][33];
  const float* src; u16* dst;
  if (blockIdx.z == 0)      { src = Wq2;             dst = Tq; }
  else if (blockIdx.z == 1) { src = Wk2;             dst = Tk; }
  else                      { src = Wv + 1024*1024;  dst = Tv; }  // bottom half of Wv
  const int k0 = blockIdx.x * 32, n0 = blockIdx.y * 32;
  const int tx = threadIdx.x, ty = threadIdx.y;
#pragma unroll
  for (int j = 0; j < 4; ++j)
    tile[ty + 8*j][tx] = src[(size_t)(k0 + ty + 8*j) * 1024 + n0 + tx];
  __syncthreads();
#pragma unroll
  for (int j = 0; j < 4; ++j)
    dst[(size_t)(n0 + ty + 8*j) * 1024 + k0 + tx] = f2bf(tile[tx][ty + 8*j]);
}

// ---------------------------------------------------------------------------
// X2 (fp32) -> bf16, 8 elems/thread
__global__ void x2bf_k(const float* __restrict__ X2, u16* __restrict__ X2b)
{
  const size_t i = ((size_t)blockIdx.x * 256 + threadIdx.x) * 8;
  f32x4 a = *(const f32x4*)(X2 + i);
  f32x4 b = *(const f32x4*)(X2 + i + 4);
  u16x8 o;
#pragma unroll
  for (int j = 0; j < 4; ++j) { o[j] = f2bf(a[j]); o[4+j] = f2bf(b[j]); }
  *(u16x8*)(X2b + i) = o;
}

// ---------------------------------------------------------------------------
// v1bv[b][d] = bv[d] + sum_j X1[b][j] * Wv[j][d]  (top half of Wv)
__global__ void v1bv_k(const float* __restrict__ X1, const float* __restrict__ Wv,
                       const float* __restrict__ bv, float* __restrict__ v1bv)
{
  const int b = blockIdx.y, t = threadIdx.x;
  const int d = blockIdx.x * 64 + (t & 63);
  const int jg = t >> 6;
  float a = 0.f;
#pragma unroll 8
  for (int jj = 0; jj < 256; ++jj) {
    const int j = jg * 256 + jj;
    a = fmaf(X1[b*1024 + j], Wv[(size_t)j * 1024 + d], a);
  }
  __shared__ float red[256];
  red[t] = a;
  __syncthreads();
  if (t < 64)
    v1bv[b*1024 + d] = red[t] + red[t+64] + red[t+128] + red[t+192] + bv[d];
}

// ---------------------------------------------------------------------------
// Projection GEMM (128^2, K=1024): C = bf16(X2b @ Wt^T + bias).
// mode 0: C row-major [16384][1024], bias[n]
// mode 1: C transposed Vt[b][n][s], bias = biasB[b*1024+n]; fused Vsum atomic.
// grid (8 n-blocks, 128 m-blocks), block 256 (4 waves, 2x2 of 64x64)
__global__ __launch_bounds__(256, 2) void gemm_proj(
    const u16* __restrict__ A, const u16* __restrict__ Bt,
    const float* __restrict__ bias, const float* __restrict__ biasB,
    u16* __restrict__ C, int mode, float* __restrict__ Vsum)
{
  __shared__ __attribute__((aligned(16))) u16 ldsA[128 * 64];
  __shared__ __attribute__((aligned(16))) u16 ldsB[128 * 64];
  const int t = threadIdx.x, lane = t & 63, w = t >> 6;
  const int wr = w >> 1, wc = w & 1, l15 = lane & 15, l4 = lane >> 4;
  const int n0 = blockIdx.x * 128, m0 = blockIdx.y * 128;
  const int ebase = w * 2048 + lane * 8;  // elem idx; + i*512

  f32x4 acc[4][4];
#pragma unroll
  for (int i = 0; i < 4; ++i)
#pragma unroll
    for (int j = 0; j < 4; ++j) acc[i][j] = (f32x4){0.f, 0.f, 0.f, 0.f};

  for (int kt = 0; kt < 16; ++kt) {
    const int k0 = kt * 64;
    __syncthreads();
#pragma unroll
    for (int i = 0; i < 4; ++i) {
      const int elem = ebase + i * 512;
      const int row = elem >> 6, col = elem & 63;
      gld16(A  + (size_t)(m0 + row) * 1024 + k0 + col, (char*)ldsA + w*4096 + i*1024);
      gld16(Bt + (size_t)(n0 + row) * 1024 + k0 + col, (char*)ldsB + w*4096 + i*1024);
    }
    __syncthreads();
#pragma unroll
    for (int inner = 0; inner < 2; ++inner) {
      bf16x8 af[4], bfr[4];
#pragma unroll
      for (int i = 0; i < 4; ++i)
        af[i] = *(const bf16x8*)&ldsA[(64*wr + 16*i + l15) * 64 + inner*32 + l4*8];
#pragma unroll
      for (int j = 0; j < 4; ++j)
        bfr[j] = *(const bf16x8*)&ldsB[(64*wc + 16*j + l15) * 64 + inner*32 + l4*8];
#pragma unroll
      for (int i = 0; i < 4; ++i)
#pragma unroll
        for (int j = 0; j < 4; ++j)
          acc[i][j] = MFMA16(af[i], bfr[j], acc[i][j]);
    }
  }

  if (mode == 0) {
#pragma unroll
    for (int j = 0; j < 4; ++j) {
      const int gc = n0 + 64*wc + 16*j + l15;
      const float bb = bias[gc];
#pragma unroll
      for (int i = 0; i < 4; ++i) {
        const int gr = m0 + 64*wr + 16*i + l4*4;
#pragma unroll
        for (int r = 0; r < 4; ++r)
          C[(size_t)(gr + r) * 1024 + gc] = f2bf(acc[i][j][r] + bb);
      }
    }
  } else {
    const int b = m0 >> 11;
#pragma unroll
    for (int j = 0; j < 4; ++j) {
      const int gc = n0 + 64*wc + 16*j + l15;            // d
      const float bb = biasB[b*1024 + gc];
      float colsum = 0.f;
#pragma unroll
      for (int i = 0; i < 4; ++i) {
        const int s = (m0 & 2047) + 64*wr + 16*i + l4*4; // seq pos
        u16x4 pk;
#pragma unroll
        for (int r = 0; r < 4; ++r) {
          const float v = acc[i][j][r] + bb;
          pk[r] = f2bf(v);
          colsum += v;
        }
        *(u16x4*)(C + (size_t)b*1024*2048 + (size_t)gc*2048 + s) = pk;
      }
      colsum += __shfl_xor(colsum, 16);
      colsum += __shfl_xor(colsum, 32);
      if (l4 == 0) atomicAdd(&Vsum[b*1024 + gc], colsum);
    }
  }
}

// ---------------------------------------------------------------------------
// Score GEMM (128^2, K=1024) with fused exp + rowsum:
// P[b,q,k] = exp((Q2[b,q,:]·K2[b,k,:]) * scale); rowsum[b*2048+q] += partials.
// 1-D grid 2048, XCD-pinned: b = id&7.
__global__ __launch_bounds__(256, 2) void gemm_sp(
    const u16* __restrict__ Q2, const u16* __restrict__ K2,
    u16* __restrict__ P, float* __restrict__ rowsum)
{
  __shared__ __attribute__((aligned(16))) u16 ldsA[128 * 64];
  __shared__ __attribute__((aligned(16))) u16 ldsB[128 * 64];
  const int id = blockIdx.x;
  const int b = id & 7, idx = id >> 3;
  const int n0 = (idx & 15) * 128, m0 = (idx >> 4) * 128;
  const int t = threadIdx.x, lane = t & 63, w = t >> 6;
  const int wr = w >> 1, wc = w & 1, l15 = lane & 15, l4 = lane >> 4;
  const u16* Ab = Q2 + (size_t)b * 2048 * 1024;
  const u16* Bb = K2 + (size_t)b * 2048 * 1024;
  u16* Cb = P + (size_t)b * 2048 * 2048;
  const int ebase = w * 2048 + lane * 8;

  f32x4 acc[4][4];
#pragma unroll
  for (int i = 0; i < 4; ++i)
#pragma unroll
    for (int j = 0; j < 4; ++j) acc[i][j] = (f32x4){0.f, 0.f, 0.f, 0.f};

  for (int kt = 0; kt < 16; ++kt) {
    const int k0 = kt * 64;
    __syncthreads();
#pragma unroll
    for (int i = 0; i < 4; ++i) {
      const int elem = ebase + i * 512;
      const int row = elem >> 6, col = elem & 63;
      gld16(Ab + (size_t)(m0 + row) * 1024 + k0 + col, (char*)ldsA + w*4096 + i*1024);
      gld16(Bb + (size_t)(n0 + row) * 1024 + k0 + col, (char*)ldsB + w*4096 + i*1024);
    }
    __syncthreads();
#pragma unroll
    for (int inner = 0; inner < 2; ++inner) {
      bf16x8 af[4], bfr[4];
#pragma unroll
      for (int i = 0; i < 4; ++i)
        af[i] = *(const bf16x8*)&ldsA[(64*wr + 16*i + l15) * 64 + inner*32 + l4*8];
#pragma unroll
      for (int j = 0; j < 4; ++j)
        bfr[j] = *(const bf16x8*)&ldsB[(64*wc + 16*j + l15) * 64 + inner*32 + l4*8];
#pragma unroll
      for (int i = 0; i < 4; ++i)
#pragma unroll
        for (int j = 0; j < 4; ++j)
          acc[i][j] = MFMA16(af[i], bfr[j], acc[i][j]);
    }
  }

  // epilogue: e = exp(scale * s); write bf16 P; accumulate row sums
  const float scale = 0.03125f;  // 1/sqrt(1024)
  float rsum[4][4];
#pragma unroll
  for (int i = 0; i < 4; ++i)
#pragma unroll
    for (int r = 0; r < 4; ++r) rsum[i][r] = 0.f;

#pragma unroll
  for (int j = 0; j < 4; ++j) {
    const int gc = n0 + 64*wc + 16*j + l15;
#pragma unroll
    for (int i = 0; i < 4; ++i) {
      const int gr = m0 + 64*wr + 16*i + l4*4;
#pragma unroll
      for (int r = 0; r < 4; ++r) {
        const float e = __expf(acc[i][j][r] * scale);
        rsum[i][r] += e;
        Cb[(size_t)(gr + r) * 2048 + gc] = f2bf(e);
      }
    }
  }
#pragma unroll
  for (int i = 0; i < 4; ++i)
#pragma unroll
    for (int r = 0; r < 4; ++r) {
      float s = rsum[i][r];
      s += __shfl_xor(s, 1);
      s += __shfl_xor(s, 2);
      s += __shfl_xor(s, 4);
      s += __shfl_xor(s, 8);
      if (l15 == 0) {
        const int gr = m0 + 64*wr + 16*i + l4*4 + r;
        atomicAdd(&rowsum[b*2048 + gr], s);
      }
    }
}

// ---------------------------------------------------------------------------
// PV GEMM (256^2, K=2048): out[b,q,d] = (P[b,q,:]·Vt[b,d,:]) / rowsum[b,q]
//                                        - (alpha/2048)*Vsum[b,d]
// 1-D grid 256, XCD-pinned b = id&7. 512 threads, 8 waves (2m x 4n),
// wave owns 128x64 output. LDS 64KB.
__global__ __launch_bounds__(512, 2) void gemm_pv256(
    const u16* __restrict__ P, const u16* __restrict__ Vt,
    const float* __restrict__ rowsum, const float* __restrict__ Vsum,
    const float* __restrict__ alphaP, float* __restrict__ out)
{
  __shared__ __attribute__((aligned(16))) u16 ldsA[256 * 64];
  __shared__ __attribute__((aligned(16))) u16 ldsB[256 * 64];
  const int id = blockIdx.x;
  const int b = id & 7, idx = id >> 3;
  const int n0 = (idx & 3) * 256, m0 = (idx >> 2) * 256;
  const int t = threadIdx.x, lane = t & 63, w = t >> 6;
  const int wr = w >> 2, wc = w & 3, l15 = lane & 15, l4 = lane >> 4;
  const u16* Ab = P  + (size_t)b * 2048 * 2048;
  const u16* Bb = Vt + (size_t)b * 1024 * 2048;

  f32x4 acc[8][4];
#pragma unroll
  for (int i = 0; i < 8; ++i)
#pragma unroll
    for (int j = 0; j < 4; ++j) acc[i][j] = (f32x4){0.f, 0.f, 0.f, 0.f};

  const int ebase = w * 512 + lane * 8;  // elem idx; + i*4096

  for (int kt = 0; kt < 32; ++kt) {
    const int k0 = kt * 64;
    __syncthreads();
#pragma unroll
    for (int i = 0; i < 4; ++i) {
      const int elem = ebase + i * 4096;
      const int row = elem >> 6, col = elem & 63;
      gld16(Ab + (size_t)(m0 + row) * 2048 + k0 + col, (char*)ldsA + i*8192 + w*1024);
      gld16(Bb + (size_t)(n0 + row) * 2048 + k0 + col, (char*)ldsB + i*8192 + w*1024);
    }
    __syncthreads();
#pragma unroll
    for (int inner = 0; inner < 2; ++inner) {
      bf16x8 af[8], bfr[4];
#pragma unroll
      for (int i = 0; i < 8; ++i)
        af[i] = *(const bf16x8*)&ldsA[(128*wr + 16*i + l15) * 64 + inner*32 + l4*8];
#pragma unroll
      for (int j = 0; j < 4; ++j)
        bfr[j] = *(const bf16x8*)&ldsB[(64*wc + 16*j + l15) * 64 + inner*32 + l4*8];
#pragma unroll
      for (int i = 0; i < 8; ++i)
#pragma unroll
        for (int j = 0; j < 4; ++j)
          acc[i][j] = MFMA16(af[i], bfr[j], acc[i][j]);
    }
  }

  const float aS = alphaP[0] * (1.0f / 2048.0f);
  float ctv[4];
#pragma unroll
  for (int j = 0; j < 4; ++j)
    ctv[j] = aS * Vsum[b*1024 + n0 + 64*wc + 16*j + l15];

#pragma unroll
  for (int i = 0; i < 8; ++i) {
    const int grb = m0 + 128*wr + 16*i + l4*4;
    float li[4];
#pragma unroll
    for (int r = 0; r < 4; ++r) li[r] = 1.0f / rowsum[b*2048 + grb + r];
#pragma unroll
    for (int j = 0; j < 4; ++j) {
      const int gc = n0 + 64*wc + 16*j + l15;
#pragma unroll
      for (int r = 0; r < 4; ++r)
        out[(size_t)(b*2048 + grb + r) * 1024 + gc] = acc[i][j][r] * li[r] - ctv[j];
    }
  }
}

// ---------------------------------------------------------------------------
extern "C" void kernel_launch(void* const* d_in, const int* in_sizes, int n_in,
                              void* d_out, int out_size, void* d_ws, size_t ws_size,
                              hipStream_t stream)
{
  const float* X1  = (const float*)d_in[0];
  const float* X2  = (const float*)d_in[1];
  const float* Wq2 = (const float*)d_in[4];
  const float* bq2 = (const float*)d_in[5];
  const float* Wk2 = (const float*)d_in[8];
  const float* bk2 = (const float*)d_in[9];
  const float* Wv  = (const float*)d_in[10];
  const float* bv  = (const float*)d_in[11];
  const float* alpha = (const float*)d_in[12];
  float* out = (float*)d_out;

  char* ws = (char*)d_ws;
  u16* Q2  = (u16*)(ws);                      // 32 MB  [16384][1024]
  u16* K2  = (u16*)(ws + 33554432);           // 32 MB
  u16* Vt  = (u16*)(ws + 67108864);           // 32 MB  [8][1024][2048]
  u16* P   = (u16*)(ws + 100663296);          // 64 MB  [8][2048][2048]
  u16* X2b = (u16*)(ws + 134217728);          // 32 MB, overlaps P upper half (dead before S-GEMM)
  u16* Tq  = (u16*)(ws + 167772160);          // 2 MB
  u16* Tk  = (u16*)(ws + 169869312);          // 2 MB
  u16* Tv  = (u16*)(ws + 171966464);          // 2 MB
  float* v1bv   = (float*)(ws + 174063616);   // 32 KB
  float* rowsum = (float*)(ws + 174096384);   // 64 KB [8][2048]
  float* Vsum   = (float*)(ws + 174161920);   // 32 KB [8][1024]

  init_k<<<24, 256, 0, stream>>>(rowsum);  // zeroes rowsum + Vsum (contiguous)
  wtrans_k<<<dim3(32, 32, 3), dim3(32, 8), 0, stream>>>(Wq2, Wk2, Wv, Tq, Tk, Tv);
  x2bf_k<<<8192, 256, 0, stream>>>(X2, X2b);
  v1bv_k<<<dim3(16, 8), 256, 0, stream>>>(X1, Wv, bv, v1bv);

  gemm_proj<<<dim3(8, 128), 256, 0, stream>>>(X2b, Tq, bq2, nullptr, Q2, 0, nullptr);
  gemm_proj<<<dim3(8, 128), 256, 0, stream>>>(X2b, Tk, bk2, nullptr, K2, 0, nullptr);
  gemm_proj<<<dim3(8, 128), 256, 0, stream>>>(X2b, Tv, nullptr, v1bv, Vt, 1, Vsum);

  gemm_sp<<<2048, 256, 0, stream>>>(Q2, K2, P, rowsum);

  gemm_pv256<<<256, 512, 0, stream>>>(P, Vt, rowsum, Vsum, alpha, out);
}

// Round 6
// 479.760 us; speedup vs baseline: 3.0994x; 1.0484x over previous
//
#include <hip/hip_runtime.h>

typedef unsigned short u16;
typedef unsigned int u32;
typedef __bf16 bf16x8 __attribute__((ext_vector_type(8)));
typedef float f32x4 __attribute__((ext_vector_type(4)));
typedef u16 u16x4 __attribute__((ext_vector_type(4)));
typedef u16 u16x8 __attribute__((ext_vector_type(8)));

#define MFMA16(a,b,c) __builtin_amdgcn_mfma_f32_16x16x32_bf16((a),(b),(c),0,0,0)

__device__ __forceinline__ u16 f2bf(float f) {
  u32 u = __builtin_bit_cast(u32, f);
  u += 0x7fffu + ((u >> 16) & 1u);   // RNE
  return (u16)(u >> 16);
}
__device__ __forceinline__ float bf2f(u16 h) {
  return __builtin_bit_cast(float, (u32)h << 16);
}

typedef __attribute__((address_space(1))) const void gas_void;
typedef __attribute__((address_space(3))) void las_void;
__device__ __forceinline__ void gld16(const void* g, void* l) {
  __builtin_amdgcn_global_load_lds((gas_void*)g, (las_void*)l, 16, 0, 0);
}

// ---------------------------------------------------------------------------
// Zero rowsum (16384 f32) + Vsum (8192 f32) — contiguous 98304 B.
__global__ void init_k(float* __restrict__ p)
{
  const int i = blockIdx.x * 256 + threadIdx.x;
  ((f32x4*)p)[i] = (f32x4){0.f, 0.f, 0.f, 0.f};
}

// ---------------------------------------------------------------------------
// Transpose + convert weights: Wt[n][k] = bf16(W[k][n]).  z selects matrix.
__global__ void wtrans_k(const float* __restrict__ Wq2, const float* __restrict__ Wk2,
                         const float* __restrict__ Wv, u16* __restrict__ Tq,
                         u16* __restrict__ Tk, u16* __restrict__ Tv)
{
  __shared__ float tile[32][33];
  const float* src; u16* dst;
  if (blockIdx.z == 0)      { src = Wq2;             dst = Tq; }
  else if (blockIdx.z == 1) { src = Wk2;             dst = Tk; }
  else                      { src = Wv + 1024*1024;  dst = Tv; }  // bottom half of Wv
  const int k0 = blockIdx.x * 32, n0 = blockIdx.y * 32;
  const int tx = threadIdx.x, ty = threadIdx.y;
#pragma unroll
  for (int j = 0; j < 4; ++j)
    tile[ty + 8*j][tx] = src[(size_t)(k0 + ty + 8*j) * 1024 + n0 + tx];
  __syncthreads();
#pragma unroll
  for (int j = 0; j < 4; ++j)
    dst[(size_t)(n0 + ty + 8*j) * 1024 + k0 + tx] = f2bf(tile[tx][ty + 8*j]);
}

// ---------------------------------------------------------------------------
// X2 (fp32) -> bf16, 8 elems/thread
__global__ void x2bf_k(const float* __restrict__ X2, u16* __restrict__ X2b)
{
  const size_t i = ((size_t)blockIdx.x * 256 + threadIdx.x) * 8;
  f32x4 a = *(const f32x4*)(X2 + i);
  f32x4 b = *(const f32x4*)(X2 + i + 4);
  u16x8 o;
#pragma unroll
  for (int j = 0; j < 4; ++j) { o[j] = f2bf(a[j]); o[4+j] = f2bf(b[j]); }
  *(u16x8*)(X2b + i) = o;
}

// ---------------------------------------------------------------------------
// v1bv[b][d] = bv[d] + sum_j X1[b][j] * Wv[j][d]  (top half of Wv)
__global__ void v1bv_k(const float* __restrict__ X1, const float* __restrict__ Wv,
                       const float* __restrict__ bv, float* __restrict__ v1bv)
{
  const int b = blockIdx.y, t = threadIdx.x;
  const int d = blockIdx.x * 64 + (t & 63);
  const int jg = t >> 6;
  float a = 0.f;
#pragma unroll 8
  for (int jj = 0; jj < 256; ++jj) {
    const int j = jg * 256 + jj;
    a = fmaf(X1[b*1024 + j], Wv[(size_t)j * 1024 + d], a);
  }
  __shared__ float red[256];
  red[t] = a;
  __syncthreads();
  if (t < 64)
    v1bv[b*1024 + d] = red[t] + red[t+64] + red[t+128] + red[t+192] + bv[d];
}

// ---------------------------------------------------------------------------
// 256x256 BK=64 GEMM core, counted-vmcnt 4-phase pipeline, swizzled LDS.
// 512 threads = 8 waves (2M x 4N); per-wave C = 128x64; LDS 128KB (2 buffers).
// K-tile split into half-K staging units (A_k0,B_k0 | A_k1,B_k1, 16KB each).
// Waits: vmcnt(8) mid-tile, vmcnt(4) boundary — never drained to 0.
// Swizzle (u16 cols within 32-col half): col ^= (row&6)<<2, applied on the
// global SOURCE of global_load_lds and on the ds_read address (both sides).
// MODE 0: proj -> row-major bf16 [.][1024], bias fa[n]
// MODE 1: proj -> Vt[b][n][s] bf16, bias fa[b*1024+n]=v1bv, atomic Vsum fm
// MODE 2: scores -> P=exp(s*scale) bf16, atomic rowsum fm
// MODE 3: PV -> out f32, linv from fa=rowsum, fb=Vsum, alphaP
template<int MODE>
__global__ __launch_bounds__(512, 2) void g256(
    const u16* __restrict__ A, const u16* __restrict__ B,
    const float* __restrict__ fa, const float* __restrict__ fb,
    float* __restrict__ fm, const float* __restrict__ alphaP,
    void* __restrict__ Cout, int K)
{
  __shared__ u16 lds[65536];  // 128 KB

  const int id = blockIdx.x;
  int b = 0, m0, n0;
  const u16 *Ab, *Bb;
  if constexpr (MODE <= 1) {          // grid 256: 4n x 64m
    n0 = (id & 3) * 256; m0 = (id >> 2) * 256;
    Ab = A; Bb = B;
    if constexpr (MODE == 1) b = m0 >> 11;
  } else if constexpr (MODE == 2) {   // grid 512: 8 batches x (8n x 8m)
    b = id & 7; const int idx = id >> 3;
    n0 = (idx & 7) * 256; m0 = (idx >> 3) * 256;
    Ab = A + (size_t)b * 2048 * 1024;
    Bb = B + (size_t)b * 2048 * 1024;
  } else {                            // grid 256: 8 batches x (4n x 8m)
    b = id & 7; const int idx = id >> 3;
    n0 = (idx & 3) * 256; m0 = (idx >> 2) * 256;
    Ab = A + (size_t)b * 2048 * 2048;
    Bb = B + (size_t)b * 1024 * 2048;
  }

  const int t = threadIdx.x, lane = t & 63, w = t >> 6;
  const int wr = w >> 2, wc = w & 3;
  const int l15 = lane & 15, l4 = lane >> 4;

  // staging: thread t loads rows (t>>2)+{0,128}, col block 8*(t&3), swizzled
  const int srow = t >> 2;
  const int scolsw = (8 * (t & 3)) ^ ((srow & 6) << 2);
  // ds_read swizzled column (u16): (l4*8) ^ ((row&6)<<2); row&6 == l15&6
  const int acolsw = (l4 * 8) ^ ((l15 & 6) << 2);
  // per-fragment LDS row bases (u16 index); half-K adds 8192, B region +16384
  const int arow = (128 * wr + l15) * 32 + acolsw;
  const int brow = 16384 + (64 * wc + l15) * 32 + acolsw;

  const u16* A0 = Ab + (size_t)(m0 + srow) * K + scolsw;
  const u16* A1 = A0 + (size_t)128 * K;
  const u16* B0 = Bb + (size_t)(n0 + srow) * K + scolsw;
  const u16* B1 = B0 + (size_t)128 * K;

  char* ldsc = (char*)lds;
  const int wo = w * 1024;

  f32x4 acc[8][4];
#pragma unroll
  for (int i = 0; i < 8; ++i)
#pragma unroll
    for (int j = 0; j < 4; ++j) acc[i][j] = (f32x4){0.f, 0.f, 0.f, 0.f};

  // ---- prologue: stage K-tile 0 into buf0 (k0 halves first, then k1)
  gld16(A0,      ldsc + wo);
  gld16(A1,      ldsc + 8192 + wo);
  gld16(B0,      ldsc + 32768 + wo);
  gld16(B1,      ldsc + 40960 + wo);
  gld16(A0 + 32, ldsc + 16384 + wo);
  gld16(A1 + 32, ldsc + 24576 + wo);
  gld16(B0 + 32, ldsc + 49152 + wo);
  gld16(B1 + 32, ldsc + 57344 + wo);
  asm volatile("s_waitcnt vmcnt(4)" ::: "memory");
  __builtin_amdgcn_s_barrier();

  const int NKT = K >> 6;
  int cur = 0;
  for (int kt = 0; kt < NKT; ++kt) {
    const int nxt = cur ^ 1;
    const size_t koff = (size_t)(kt + 1) * 64;
    char* dst = ldsc + nxt * 65536 + wo;
    const u16* la0 = lds + cur * 32768;

    bf16x8 af[8], p0, p1;

    // ---- phase 0: stage k0-half of kt+1; compute kk0, C-left (j=0,1)
    gld16(A0 + koff, dst);
    gld16(A1 + koff, dst + 8192);
    gld16(B0 + koff, dst + 32768);
    gld16(B1 + koff, dst + 40960);
#pragma unroll
    for (int m = 0; m < 8; ++m) af[m] = *(const bf16x8*)(la0 + arow + m * 512);
    p0 = *(const bf16x8*)(la0 + brow);
    p1 = *(const bf16x8*)(la0 + brow + 512);
    __builtin_amdgcn_s_setprio(1);
#pragma unroll
    for (int m = 0; m < 8; ++m) {
      acc[m][0] = MFMA16(af[m], p0, acc[m][0]);
      acc[m][1] = MFMA16(af[m], p1, acc[m][1]);
    }
    __builtin_amdgcn_s_setprio(0);

    // ---- phase 1: stage k1-half of kt+1; compute kk0, C-right (j=2,3)
    gld16(A0 + koff + 32, dst + 16384);
    gld16(A1 + koff + 32, dst + 24576);
    gld16(B0 + koff + 32, dst + 49152);
    gld16(B1 + koff + 32, dst + 57344);
    p0 = *(const bf16x8*)(la0 + brow + 1024);
    p1 = *(const bf16x8*)(la0 + brow + 1536);
    __builtin_amdgcn_s_setprio(1);
#pragma unroll
    for (int m = 0; m < 8; ++m) {
      acc[m][2] = MFMA16(af[m], p0, acc[m][2]);
      acc[m][3] = MFMA16(af[m], p1, acc[m][3]);
    }
    __builtin_amdgcn_s_setprio(0);

    // mid-tile: own k1 halves of kt (oldest) must be landed; kt+1's 8 stay out
    asm volatile("s_waitcnt vmcnt(8)" ::: "memory");
    __builtin_amdgcn_s_barrier();

    // ---- phase 2: compute kk1, C-left
#pragma unroll
    for (int m = 0; m < 8; ++m) af[m] = *(const bf16x8*)(la0 + 8192 + arow + m * 512);
    p0 = *(const bf16x8*)(la0 + 8192 + brow);
    p1 = *(const bf16x8*)(la0 + 8192 + brow + 512);
    __builtin_amdgcn_s_setprio(1);
#pragma unroll
    for (int m = 0; m < 8; ++m) {
      acc[m][0] = MFMA16(af[m], p0, acc[m][0]);
      acc[m][1] = MFMA16(af[m], p1, acc[m][1]);
    }
    __builtin_amdgcn_s_setprio(0);

    // ---- phase 3: compute kk1, C-right
    p0 = *(const bf16x8*)(la0 + 8192 + brow + 1024);
    p1 = *(const bf16x8*)(la0 + 8192 + brow + 1536);
    __builtin_amdgcn_s_setprio(1);
#pragma unroll
    for (int m = 0; m < 8; ++m) {
      acc[m][2] = MFMA16(af[m], p0, acc[m][2]);
      acc[m][3] = MFMA16(af[m], p1, acc[m][3]);
    }
    __builtin_amdgcn_s_setprio(0);

    // boundary: kt+1's k0 halves (oldest 4) landed; its k1 (4) stay in flight
    asm volatile("s_waitcnt vmcnt(4)" ::: "memory");
    __builtin_amdgcn_s_barrier();
    cur = nxt;
  }

  // ---- epilogues
  if constexpr (MODE == 0) {
    u16* C = (u16*)Cout;
#pragma unroll
    for (int j = 0; j < 4; ++j) {
      const int gc = n0 + 64*wc + 16*j + l15;
      const float bb = fa[gc];
#pragma unroll
      for (int i = 0; i < 8; ++i) {
        const int gr = m0 + 128*wr + 16*i + l4*4;
#pragma unroll
        for (int r = 0; r < 4; ++r)
          C[(size_t)(gr + r) * 1024 + gc] = f2bf(acc[i][j][r] + bb);
      }
    }
  } else if constexpr (MODE == 1) {
    u16* C = (u16*)Cout;
#pragma unroll
    for (int j = 0; j < 4; ++j) {
      const int gc = n0 + 64*wc + 16*j + l15;            // d
      const float bb = fa[b*1024 + gc];
      float colsum = 0.f;
#pragma unroll
      for (int i = 0; i < 8; ++i) {
        const int s = (m0 & 2047) + 128*wr + 16*i + l4*4; // seq pos
        u16x4 pk;
#pragma unroll
        for (int r = 0; r < 4; ++r) {
          const float v = acc[i][j][r] + bb;
          pk[r] = f2bf(v);
          colsum += v;
        }
        *(u16x4*)(C + (size_t)b*1024*2048 + (size_t)gc*2048 + s) = pk;
      }
      colsum += __shfl_xor(colsum, 16);
      colsum += __shfl_xor(colsum, 32);
      if (l4 == 0) atomicAdd(&fm[b*1024 + gc], colsum);
    }
  } else if constexpr (MODE == 2) {
    u16* Cb = (u16*)Cout + (size_t)b * 2048 * 2048;
    const float scale = 0.03125f;  // 1/sqrt(1024)
    float rs[8][4];
#pragma unroll
    for (int i = 0; i < 8; ++i)
#pragma unroll
      for (int r = 0; r < 4; ++r) rs[i][r] = 0.f;
#pragma unroll
    for (int j = 0; j < 4; ++j) {
      const int gc = n0 + 64*wc + 16*j + l15;
#pragma unroll
      for (int i = 0; i < 8; ++i) {
        const int gr = m0 + 128*wr + 16*i + l4*4;
#pragma unroll
        for (int r = 0; r < 4; ++r) {
          const float e = __expf(acc[i][j][r] * scale);
          rs[i][r] += e;
          Cb[(size_t)(gr + r) * 2048 + gc] = f2bf(e);
        }
      }
    }
#pragma unroll
    for (int i = 0; i < 8; ++i)
#pragma unroll
      for (int r = 0; r < 4; ++r) {
        float s = rs[i][r];
        s += __shfl_xor(s, 1);
        s += __shfl_xor(s, 2);
        s += __shfl_xor(s, 4);
        s += __shfl_xor(s, 8);
        if (l15 == 0) {
          const int gr = m0 + 128*wr + 16*i + l4*4 + r;
          atomicAdd(&fm[b*2048 + gr], s);
        }
      }
  } else {
    float* out = (float*)Cout;
    const float aS = alphaP[0] * (1.0f / 2048.0f);
    float ctv[4];
#pragma unroll
    for (int j = 0; j < 4; ++j)
      ctv[j] = aS * fb[b*1024 + n0 + 64*wc + 16*j + l15];
#pragma unroll
    for (int i = 0; i < 8; ++i) {
      const int grb = m0 + 128*wr + 16*i + l4*4;
      float li[4];
#pragma unroll
      for (int r = 0; r < 4; ++r) li[r] = 1.0f / fa[b*2048 + grb + r];
#pragma unroll
      for (int j = 0; j < 4; ++j) {
        const int gc = n0 + 64*wc + 16*j + l15;
#pragma unroll
        for (int r = 0; r < 4; ++r)
          out[(size_t)(b*2048 + grb + r) * 1024 + gc] = acc[i][j][r] * li[r] - ctv[j];
      }
    }
  }
}

// ---------------------------------------------------------------------------
extern "C" void kernel_launch(void* const* d_in, const int* in_sizes, int n_in,
                              void* d_out, int out_size, void* d_ws, size_t ws_size,
                              hipStream_t stream)
{
  const float* X1  = (const float*)d_in[0];
  const float* X2  = (const float*)d_in[1];
  const float* Wq2 = (const float*)d_in[4];
  const float* bq2 = (const float*)d_in[5];
  const float* Wk2 = (const float*)d_in[8];
  const float* bk2 = (const float*)d_in[9];
  const float* Wv  = (const float*)d_in[10];
  const float* bv  = (const float*)d_in[11];
  const float* alpha = (const float*)d_in[12];
  float* out = (float*)d_out;

  char* ws = (char*)d_ws;
  u16* Q2  = (u16*)(ws);                      // 32 MB  [16384][1024]
  u16* K2  = (u16*)(ws + 33554432);           // 32 MB
  u16* Vt  = (u16*)(ws + 67108864);           // 32 MB  [8][1024][2048]
  u16* P   = (u16*)(ws + 100663296);          // 64 MB  [8][2048][2048]
  u16* X2b = (u16*)(ws + 134217728);          // 32 MB, overlaps P upper half (dead before S-GEMM)
  u16* Tq  = (u16*)(ws + 167772160);          // 2 MB
  u16* Tk  = (u16*)(ws + 169869312);          // 2 MB
  u16* Tv  = (u16*)(ws + 171966464);          // 2 MB
  float* v1bv   = (float*)(ws + 174063616);   // 32 KB
  float* rowsum = (float*)(ws + 174096384);   // 64 KB [8][2048]
  float* Vsum   = (float*)(ws + 174161920);   // 32 KB [8][1024]

  init_k<<<24, 256, 0, stream>>>(rowsum);  // zeroes rowsum + Vsum (contiguous)
  wtrans_k<<<dim3(32, 32, 3), dim3(32, 8), 0, stream>>>(Wq2, Wk2, Wv, Tq, Tk, Tv);
  x2bf_k<<<8192, 256, 0, stream>>>(X2, X2b);
  v1bv_k<<<dim3(16, 8), 256, 0, stream>>>(X1, Wv, bv, v1bv);

  g256<0><<<256, 512, 0, stream>>>(X2b, Tq, bq2, nullptr, nullptr, nullptr, Q2, 1024);
  g256<0><<<256, 512, 0, stream>>>(X2b, Tk, bk2, nullptr, nullptr, nullptr, K2, 1024);
  g256<1><<<256, 512, 0, stream>>>(X2b, Tv, v1bv, nullptr, Vsum, nullptr, Vt, 1024);

  g256<2><<<512, 512, 0, stream>>>(Q2, K2, nullptr, nullptr, rowsum, nullptr, P, 1024);

  g256<3><<<256, 512, 0, stream>>>(P, Vt, rowsum, Vsum, nullptr, alpha, out, 2048);
}

// Round 10
// 421.301 us; speedup vs baseline: 3.5295x; 1.1388x over previous
//
#include <hip/hip_runtime.h>

typedef unsigned short u16;
typedef unsigned int u32;
typedef __bf16 bf16x8 __attribute__((ext_vector_type(8)));
typedef float f32x4 __attribute__((ext_vector_type(4)));
typedef u16 u16x4 __attribute__((ext_vector_type(4)));
typedef u16 u16x8 __attribute__((ext_vector_type(8)));

#define MFMA16(a,b,c) __builtin_amdgcn_mfma_f32_16x16x32_bf16((a),(b),(c),0,0,0)

__device__ __forceinline__ u16 f2bf(float f) {
  u32 u = __builtin_bit_cast(u32, f);
  u += 0x7fffu + ((u >> 16) & 1u);   // RNE
  return (u16)(u >> 16);
}
__device__ __forceinline__ float bf2f(u16 h) {
  return __builtin_bit_cast(float, (u32)h << 16);
}

typedef __attribute__((address_space(1))) const void gas_void;
typedef __attribute__((address_space(3))) void las_void;
__device__ __forceinline__ void gld16(const void* g, void* l) {
  __builtin_amdgcn_global_load_lds((gas_void*)g, (las_void*)l, 16, 0, 0);
}

// ---------------------------------------------------------------------------
// Zero rowsum (16384 f32) + Vsum (8192 f32) — contiguous 98304 B.
__global__ void init_k(float* __restrict__ p)
{
  const int i = blockIdx.x * 256 + threadIdx.x;
  ((f32x4*)p)[i] = (f32x4){0.f, 0.f, 0.f, 0.f};
}

// ---------------------------------------------------------------------------
// Transpose + convert weights: Wt[n][k] = bf16(W[k][n]).  z selects matrix.
__global__ void wtrans_k(const float* __restrict__ Wq2, const float* __restrict__ Wk2,
                         const float* __restrict__ Wv, u16* __restrict__ Tq,
                         u16* __restrict__ Tk, u16* __restrict__ Tv)
{
  __shared__ float tile[32][33];
  const float* src; u16* dst;
  if (blockIdx.z == 0)      { src = Wq2;             dst = Tq; }
  else if (blockIdx.z == 1) { src = Wk2;             dst = Tk; }
  else                      { src = Wv + 1024*1024;  dst = Tv; }  // bottom half of Wv
  const int k0 = blockIdx.x * 32, n0 = blockIdx.y * 32;
  const int tx = threadIdx.x, ty = threadIdx.y;
#pragma unroll
  for (int j = 0; j < 4; ++j)
    tile[ty + 8*j][tx] = src[(size_t)(k0 + ty + 8*j) * 1024 + n0 + tx];
  __syncthreads();
#pragma unroll
  for (int j = 0; j < 4; ++j)
    dst[(size_t)(n0 + ty + 8*j) * 1024 + k0 + tx] = f2bf(tile[tx][ty + 8*j]);
}

// ---------------------------------------------------------------------------
// X2 (fp32) -> bf16, 8 elems/thread
__global__ void x2bf_k(const float* __restrict__ X2, u16* __restrict__ X2b)
{
  const size_t i = ((size_t)blockIdx.x * 256 + threadIdx.x) * 8;
  f32x4 a = *(const f32x4*)(X2 + i);
  f32x4 b = *(const f32x4*)(X2 + i + 4);
  u16x8 o;
#pragma unroll
  for (int j = 0; j < 4; ++j) { o[j] = f2bf(a[j]); o[4+j] = f2bf(b[j]); }
  *(u16x8*)(X2b + i) = o;
}

// ---------------------------------------------------------------------------
// v1bv[b][d] = bv[d] + sum_j X1[b][j] * Wv[j][d]  (top half of Wv)
__global__ void v1bv_k(const float* __restrict__ X1, const float* __restrict__ Wv,
                       const float* __restrict__ bv, float* __restrict__ v1bv)
{
  const int b = blockIdx.y, t = threadIdx.x;
  const int d = blockIdx.x * 64 + (t & 63);
  const int jg = t >> 6;
  float a = 0.f;
#pragma unroll 8
  for (int jj = 0; jj < 256; ++jj) {
    const int j = jg * 256 + jj;
    a = fmaf(X1[b*1024 + j], Wv[(size_t)j * 1024 + d], a);
  }
  __shared__ float red[256];
  red[t] = a;
  __syncthreads();
  if (t < 64)
    v1bv[b*1024 + d] = red[t] + red[t+64] + red[t+128] + red[t+192] + bv[d];
}

// ---------------------------------------------------------------------------
// 256x256 BK=64 GEMM, m201-style 8-phase schedule (2 K-tiles / iter).
// 512 threads = 8 waves (2M x 4N); per-wave C = 128x64. LDS 128KB:
//   A: [2 buf][2 half][128 rows][64 u16]   bytes 0..65535
//   B: same                                bytes 65536..131071
// Row = 128B (full line). Swizzle: 16B chunk c within a row stored/read at
// c ^ (row&7) (involution, both-sides: gld16 source + ds_read addr).
// Per phase: {ds_read subtile, stage 1 half-tile(2 gld16)} -> barrier ->
// lgkmcnt(0) -> setprio(1) 16 MFMA setprio(0) -> [vmcnt(2) @ph4,ph8] barrier.
// Stage stream iter i (tiles T=2i,T+1): ph1-3: B1,A0,A1 of T+1; ph4-7:
// B0,A0,A1,B1 of T+2; ph8: B0 of T+3. Tail: clamp tile idx (re-stage = same
// bytes, benign).
// MODE 0: C row-major bf16 [.][1024], bias fa[n]
// MODE 1: C = Vt[b][n][s] bf16, bias fa[b*1024+n], atomic Vsum fm
// MODE 2: P = exp(s*scale) bf16, atomic rowsum fm
// MODE 3: out f32 = acc/rowsum - (alpha/2048)*Vsum
template<int MODE>
__global__ __launch_bounds__(512, 2) void g256(
    const u16* __restrict__ A, const u16* __restrict__ B,
    const float* __restrict__ fa, const float* __restrict__ fb,
    float* __restrict__ fm, const float* __restrict__ alphaP,
    void* __restrict__ Cout, int K)
{
  __shared__ u16 lds[65536];  // 128 KB

  const int id = blockIdx.x;
  int b = 0, m0, n0;
  const u16 *Ab, *Bb;
  if constexpr (MODE <= 1) {          // grid 256: 4n x 64m
    n0 = (id & 3) * 256; m0 = (id >> 2) * 256;
    Ab = A; Bb = B;
    if constexpr (MODE == 1) b = m0 >> 11;
  } else if constexpr (MODE == 2) {   // grid 512: 8 batches x (8n x 8m)
    b = id & 7; const int idx = id >> 3;
    n0 = (idx & 7) * 256; m0 = (idx >> 3) * 256;
    Ab = A + (size_t)b * 2048 * 1024;
    Bb = B + (size_t)b * 2048 * 1024;
  } else {                            // grid 256: 8 batches x (4n x 8m)
    b = id & 7; const int idx = id >> 3;
    n0 = (idx & 3) * 256; m0 = (idx >> 2) * 256;
    Ab = A + (size_t)b * 2048 * 2048;
    Bb = B + (size_t)b * 1024 * 2048;
  }

  const int t = threadIdx.x, lane = t & 63, w = t >> 6;
  const int wr = w >> 2, wc = w & 3;
  const int l15 = lane & 15, l4 = lane >> 4;

  // ds_read swizzled chunk offsets (u16) for kk=0 / kk=1
  const int cs0 = (l4 ^ (l15 & 7)) * 8;
  const int cs1 = ((4 + l4) ^ (l15 & 7)) * 8;
  // read bases (u16 index): + buf*16384 + m(or j)*1024 + cs
  const int aBase = wr * 8192 + l15 * 64;
  const int bBase = 32768 + (wc >> 1) * 8192 + (wc & 1) * 4096 + l15 * 64;

  // staging: thread t -> row t>>3 (of 64 per gld16), chunk (t&7) ^ (row&7)
  const int srow = t >> 3;
  const int scol = ((t & 7) ^ (srow & 7)) * 8;  // u16
  const u16* As = Ab + (size_t)(m0 + srow) * K + scol;
  const u16* Bs = Bb + (size_t)(n0 + srow) * K + scol;
  char* ldsc = (char*)lds;
  const int wdst = w * 1024;
  const int NKT = K >> 6;

  auto stA = [&](int s, int h) {
    const size_t ro = (size_t)(128 * h) * K + (size_t)s * 64;
    char* d = ldsc + (s & 1) * 32768 + h * 16384 + wdst;
    gld16(As + ro, d);
    gld16(As + ro + (size_t)64 * K, d + 8192);
  };
  auto stB = [&](int s, int h) {
    const size_t ro = (size_t)(128 * h) * K + (size_t)s * 64;
    char* d = ldsc + 65536 + (s & 1) * 32768 + h * 16384 + wdst;
    gld16(Bs + ro, d);
    gld16(Bs + ro + (size_t)64 * K, d + 8192);
  };

  f32x4 acc[8][4];
#pragma unroll
  for (int i = 0; i < 8; ++i)
#pragma unroll
    for (int j = 0; j < 4; ++j) acc[i][j] = (f32x4){0.f, 0.f, 0.f, 0.f};

  bf16x8 af[4], bfr[4];
  auto rdA = [&](int buf, int mlo, int kkcs) {
    const int base = buf * 16384 + aBase + kkcs;
#pragma unroll
    for (int m = 0; m < 4; ++m)
      af[m] = *(const bf16x8*)&lds[base + (mlo + m) * 1024];
  };
  auto rdB = [&](int buf, int kkcs) {
    const int base = buf * 16384 + bBase + kkcs;
#pragma unroll
    for (int j = 0; j < 4; ++j)
      bfr[j] = *(const bf16x8*)&lds[base + j * 1024];
  };
  auto mm = [&](int mlo) {
#pragma unroll
    for (int m = 0; m < 4; ++m)
#pragma unroll
      for (int j = 0; j < 4; ++j)
        acc[mlo + m][j] = MFMA16(af[m], bfr[j], acc[mlo + m][j]);
  };

#define PH_MID                                              \
  __builtin_amdgcn_s_barrier();                             \
  asm volatile("s_waitcnt lgkmcnt(0)" ::: "memory");        \
  __builtin_amdgcn_sched_barrier(0);                        \
  __builtin_amdgcn_s_setprio(1);
#define PH_END                                              \
  __builtin_amdgcn_s_setprio(0);                            \
  __builtin_amdgcn_s_barrier();
#define PH_ENDV                                             \
  __builtin_amdgcn_s_setprio(0);                            \
  asm volatile("s_waitcnt vmcnt(2)" ::: "memory");          \
  __builtin_amdgcn_sched_barrier(0);                        \
  __builtin_amdgcn_s_barrier();

  // prologue: tile0 complete + tile1.B0; wait all but last half-tile
  stA(0, 0); stA(0, 1); stB(0, 0); stB(0, 1);
  stB(1, 0);
  asm volatile("s_waitcnt vmcnt(2)" ::: "memory");
  __builtin_amdgcn_sched_barrier(0);
  __builtin_amdgcn_s_barrier();

  const int NI = NKT >> 1;
  for (int i = 0; i < NI; ++i) {
    const int T = 2 * i;
    const int s1 = T + 1;
    const int s2 = (T + 2 < NKT) ? T + 2 : NKT - 1;
    const int s3 = (T + 3 < NKT) ? T + 3 : NKT - 1;

    // ph1: buf0 kk0 m0-3 (+B kk0)   | stage B1(s1)
    rdA(0, 0, cs0); rdB(0, cs0); stB(s1, 1);
    PH_MID; mm(0); PH_END;
    // ph2: buf0 kk0 m4-7            | stage A0(s1)
    rdA(0, 4, cs0); stA(s1, 0);
    PH_MID; mm(4); PH_END;
    // ph3: buf0 kk1 m0-3 (+B kk1)   | stage A1(s1)
    rdA(0, 0, cs1); rdB(0, cs1); stA(s1, 1);
    PH_MID; mm(0); PH_END;
    // ph4: buf0 kk1 m4-7            | stage B0(s2) | vmcnt(2)
    rdA(0, 4, cs1); stB(s2, 0);
    PH_MID; mm(4); PH_ENDV;

    // ph5: buf1 kk0 m0-3 (+B kk0)   | stage A0(s2)
    rdA(1, 0, cs0); rdB(1, cs0); stA(s2, 0);
    PH_MID; mm(0); PH_END;
    // ph6: buf1 kk0 m4-7            | stage A1(s2)
    rdA(1, 4, cs0); stA(s2, 1);
    PH_MID; mm(4); PH_END;
    // ph7: buf1 kk1 m0-3 (+B kk1)   | stage B1(s2)
    rdA(1, 0, cs1); rdB(1, cs1); stB(s2, 1);
    PH_MID; mm(0); PH_END;
    // ph8: buf1 kk1 m4-7            | stage B0(s3) | vmcnt(2)
    rdA(1, 4, cs1); stB(s3, 0);
    PH_MID; mm(4); PH_ENDV;
  }
  asm volatile("s_waitcnt vmcnt(0)" ::: "memory");
#undef PH_MID
#undef PH_END
#undef PH_ENDV

  // ---- epilogues
  if constexpr (MODE == 0) {
    u16* C = (u16*)Cout;
    float bb[4];
#pragma unroll
    for (int j = 0; j < 4; ++j) bb[j] = fa[n0 + 64*wc + 16*j + l15];
#pragma unroll
    for (int i = 0; i < 8; ++i)
#pragma unroll
      for (int r = 0; r < 4; ++r) {
        const int gr = m0 + 128*wr + 16*i + l4*4 + r;
#pragma unroll
        for (int j = 0; j < 4; ++j) {
          const int gc = n0 + 64*wc + 16*j + l15;
          C[(size_t)gr * 1024 + gc] = f2bf(acc[i][j][r] + bb[j]);
        }
      }
  } else if constexpr (MODE == 1) {
    u16* C = (u16*)Cout;
#pragma unroll
    for (int j = 0; j < 4; ++j) {
      const int gc = n0 + 64*wc + 16*j + l15;            // d
      const float bb = fa[b*1024 + gc];
      float colsum = 0.f;
#pragma unroll
      for (int i = 0; i < 8; ++i) {
        const int s = (m0 & 2047) + 128*wr + 16*i + l4*4; // seq pos
        u16x4 pk;
#pragma unroll
        for (int r = 0; r < 4; ++r) {
          const float v = acc[i][j][r] + bb;
          pk[r] = f2bf(v);
          colsum += v;
        }
        *(u16x4*)(C + (size_t)b*1024*2048 + (size_t)gc*2048 + s) = pk;
      }
      colsum += __shfl_xor(colsum, 16);
      colsum += __shfl_xor(colsum, 32);
      if (l4 == 0) atomicAdd(&fm[b*1024 + gc], colsum);
    }
  } else if constexpr (MODE == 2) {
    u16* Cb = (u16*)Cout + (size_t)b * 2048 * 2048;
    const float scale = 0.03125f;  // 1/sqrt(1024)
#pragma unroll
    for (int i = 0; i < 8; ++i) {
      float rs[4] = {0.f, 0.f, 0.f, 0.f};
#pragma unroll
      for (int r = 0; r < 4; ++r) {
        const int gr = m0 + 128*wr + 16*i + l4*4 + r;
#pragma unroll
        for (int j = 0; j < 4; ++j) {
          const int gc = n0 + 64*wc + 16*j + l15;
          const float e = __expf(acc[i][j][r] * scale);
          rs[r] += e;
          Cb[(size_t)gr * 2048 + gc] = f2bf(e);
        }
      }
#pragma unroll
      for (int r = 0; r < 4; ++r) {
        float s = rs[r];
        s += __shfl_xor(s, 1);
        s += __shfl_xor(s, 2);
        s += __shfl_xor(s, 4);
        s += __shfl_xor(s, 8);
        if (l15 == 0) {
          const int gr = m0 + 128*wr + 16*i + l4*4 + r;
          atomicAdd(&fm[b*2048 + gr], s);
        }
      }
    }
  } else {
    float* out = (float*)Cout;
    const float aS = alphaP[0] * (1.0f / 2048.0f);
    float ctv[4];
#pragma unroll
    for (int j = 0; j < 4; ++j)
      ctv[j] = aS * fb[b*1024 + n0 + 64*wc + 16*j + l15];
#pragma unroll
    for (int i = 0; i < 8; ++i) {
#pragma unroll
      for (int r = 0; r < 4; ++r) {
        const int gr = m0 + 128*wr + 16*i + l4*4 + r;
        const float li = 1.0f / fa[b*2048 + gr];
#pragma unroll
        for (int j = 0; j < 4; ++j) {
          const int gc = n0 + 64*wc + 16*j + l15;
          out[(size_t)(b*2048 + gr) * 1024 + gc] = acc[i][j][r] * li - ctv[j];
        }
      }
    }
  }
}

// ---------------------------------------------------------------------------
extern "C" void kernel_launch(void* const* d_in, const int* in_sizes, int n_in,
                              void* d_out, int out_size, void* d_ws, size_t ws_size,
                              hipStream_t stream)
{
  const float* X1  = (const float*)d_in[0];
  const float* X2  = (const float*)d_in[1];
  const float* Wq2 = (const float*)d_in[4];
  const float* bq2 = (const float*)d_in[5];
  const float* Wk2 = (const float*)d_in[8];
  const float* bk2 = (const float*)d_in[9];
  const float* Wv  = (const float*)d_in[10];
  const float* bv  = (const float*)d_in[11];
  const float* alpha = (const float*)d_in[12];
  float* out = (float*)d_out;

  char* ws = (char*)d_ws;
  u16* Q2  = (u16*)(ws);                      // 32 MB  [16384][1024]
  u16* K2  = (u16*)(ws + 33554432);           // 32 MB
  u16* Vt  = (u16*)(ws + 67108864);           // 32 MB  [8][1024][2048]
  u16* P   = (u16*)(ws + 100663296);          // 64 MB  [8][2048][2048]
  u16* X2b = (u16*)(ws + 134217728);          // 32 MB, overlaps P upper half (dead before S-GEMM)
  u16* Tq  = (u16*)(ws + 167772160);          // 2 MB
  u16* Tk  = (u16*)(ws + 169869312);          // 2 MB
  u16* Tv  = (u16*)(ws + 171966464);          // 2 MB
  float* v1bv   = (float*)(ws + 174063616);   // 32 KB
  float* rowsum = (float*)(ws + 174096384);   // 64 KB [8][2048]
  float* Vsum   = (float*)(ws + 174161920);   // 32 KB [8][1024]

  init_k<<<24, 256, 0, stream>>>(rowsum);  // zeroes rowsum + Vsum (contiguous)
  wtrans_k<<<dim3(32, 32, 3), dim3(32, 8), 0, stream>>>(Wq2, Wk2, Wv, Tq, Tk, Tv);
  x2bf_k<<<8192, 256, 0, stream>>>(X2, X2b);
  v1bv_k<<<dim3(16, 8), 256, 0, stream>>>(X1, Wv, bv, v1bv);

  g256<0><<<256, 512, 0, stream>>>(X2b, Tq, bq2, nullptr, nullptr, nullptr, Q2, 1024);
  g256<0><<<256, 512, 0, stream>>>(X2b, Tk, bk2, nullptr, nullptr, nullptr, K2, 1024);
  g256<1><<<256, 512, 0, stream>>>(X2b, Tv, v1bv, nullptr, Vsum, nullptr, Vt, 1024);

  g256<2><<<512, 512, 0, stream>>>(Q2, K2, nullptr, nullptr, rowsum, nullptr, P, 1024);

  g256<3><<<256, 512, 0, stream>>>(P, Vt, rowsum, Vsum, nullptr, alpha, out, 2048);
}